// Round 8
// baseline (630.601 us; speedup 1.0000x reference)
//
#include <hip/hip_runtime.h>
#include <hip/hip_bf16.h>
#include <stdint.h>

// Problem constants
#define B_  4
#define S_  2048
#define D_  1024
#define H_  16
#define DH_ 64
#define N3_ 3072   // 3*D

typedef __attribute__((ext_vector_type(8))) short  short8;   // 8 bf16 (4 VGPRs)
typedef __attribute__((ext_vector_type(8))) unsigned short ushort8;
typedef __attribute__((ext_vector_type(4))) float  float4v;  // 4 fp32 acc

__device__ __forceinline__ float bf2f(unsigned short u) {
    union { unsigned int i; float f; } c; c.i = ((unsigned int)u) << 16; return c.f;
}
__device__ __forceinline__ unsigned short f2bf(float f) {
    union { float f; unsigned int i; } c; c.f = f;
    unsigned int x = c.i;
    return (unsigned short)((x + 0x7FFFu + ((x >> 16) & 1u)) >> 16);  // RNE
}
__device__ __forceinline__ unsigned short f2bf_hu(float f) {   // half-up (cheap)
    union { float f; unsigned int i; } c; c.f = f;
    return (unsigned short)((c.i + 0x8000u) >> 16);
}

// async global->LDS DMA, 16B per lane; LDS dest = wave-uniform base + lane*16
__device__ __forceinline__ void gll16(const void* g, void* l) {
    __builtin_amdgcn_global_load_lds(
        (const __attribute__((address_space(1))) unsigned int*)g,
        (__attribute__((address_space(3))) unsigned int*)l, 16, 0, 0);
}

// ---------------------------------------------------------------------------
// fp32 -> bf16 elementwise (x). 8 elems/thread.
// ---------------------------------------------------------------------------
__global__ __launch_bounds__(256) void convert_x(
    const float* __restrict__ in, unsigned short* __restrict__ out, int n8)
{
    int g = blockIdx.x * 256 + threadIdx.x;
    if (g >= n8) return;
    const float4* p = (const float4*)(in + (size_t)g * 8);
    float4 a = p[0], b = p[1];
    ushort8 o;
    o[0] = f2bf(a.x); o[1] = f2bf(a.y); o[2] = f2bf(a.z); o[3] = f2bf(a.w);
    o[4] = f2bf(b.x); o[5] = f2bf(b.y); o[6] = f2bf(b.z); o[7] = f2bf(b.w);
    *(ushort8*)(out + (size_t)g * 8) = o;
}

// ---------------------------------------------------------------------------
// fp32 [K][N] -> bf16 [N][K] transpose (weights). 32x32 LDS tile, 256 thr.
// ---------------------------------------------------------------------------
__global__ __launch_bounds__(256) void convert_wT(
    const float* __restrict__ w, unsigned short* __restrict__ wt, int K, int N)
{
    __shared__ float t[32][33];
    const int row = threadIdx.x >> 5;   // 0..7
    const int col = threadIdx.x & 31;   // 0..31
    const int n0 = blockIdx.x * 32;
    const int k0 = blockIdx.y * 32;
#pragma unroll
    for (int i = 0; i < 4; ++i)
        t[row + 8 * i][col] = w[(size_t)(k0 + row + 8 * i) * N + n0 + col];
    __syncthreads();
#pragma unroll
    for (int i = 0; i < 4; ++i)
        wt[(size_t)(n0 + row + 8 * i) * K + k0 + col] = f2bf(t[col][row + 8 * i]);
}

// ---------------------------------------------------------------------------
// bf16 MFMA GEMM: C[M,N] = A[M,K] @ Bt[N,K]^T + bias.
// 128x128 tile, BK=64, 4 waves, each wave 64x64 (4x4 MFMA tiles).
// Main loop unchanged (m97-structure, XOR-swizzled global_load_lds staging).
// MODE 0 epilogue: all outputs routed through wave-private 8KB LDS region
//   (free after k-loop), stored with coalesced wide instructions:
//    - V  : transpose to [dh][s], 2x (4x dwordx4) per lane
//    - Q/K: reshape [s][dh], 8x 1KB dwordx4 stores
// MODE 1: fp32 out [M][N] (N=1024).
// ---------------------------------------------------------------------------
template <int MODE>
__global__ __launch_bounds__(256) void gemm_bt(
    const unsigned short* __restrict__ a, const unsigned short* __restrict__ bt,
    const float* __restrict__ bias,
    unsigned short* __restrict__ q, unsigned short* __restrict__ k,
    unsigned short* __restrict__ v, float* __restrict__ out,
    int K, int N)
{
    __shared__ unsigned short As[128][64];   // unpadded: 16 KB each
    __shared__ unsigned short Bs[128][64];

    const int tid  = threadIdx.x;
    const int wave = tid >> 6;
    const int lane = tid & 63;
    const int col  = lane & 15;
    const int quad = lane >> 4;
    const int wm   = (wave & 1) * 64;
    const int wn   = (wave >> 1) * 64;

    const int m0 = blockIdx.y * 128;
    const int n0 = blockIdx.x * 128;

    const int srow0 = wave * 32 + (lane >> 3);
    const int scg   = (lane & 7) ^ (lane >> 3);

    float4v acc[4][4] = {};

    for (int kt = 0; kt < K; kt += 64) {
#pragma unroll
        for (int c = 0; c < 4; ++c) {
            int row = srow0 + c * 8;
            gll16(a  + (size_t)(m0 + row) * K + kt + scg * 8,
                  (char*)As + wave * 4096 + c * 1024);
            gll16(bt + (size_t)(n0 + row) * K + kt + scg * 8,
                  (char*)Bs + wave * 4096 + c * 1024);
        }
        __syncthreads();   // drains vmcnt (incl. global_load_lds)

#pragma unroll
        for (int ks = 0; ks < 64; ks += 32) {
            const int sa = (((ks >> 3) + quad) ^ (col & 7)) * 8;  // swizzled offset
            short8 af[4], bf[4];
#pragma unroll
            for (int mi = 0; mi < 4; ++mi)
                af[mi] = *(const short8*)&As[wm + mi * 16 + col][sa];
#pragma unroll
            for (int ni = 0; ni < 4; ++ni)
                bf[ni] = *(const short8*)&Bs[wn + ni * 16 + col][sa];
#pragma unroll
            for (int mi = 0; mi < 4; ++mi)
#pragma unroll
                for (int ni = 0; ni < 4; ++ni)
                    acc[mi][ni] = __builtin_amdgcn_mfma_f32_16x16x32_bf16(
                        af[mi], bf[ni], acc[mi][ni], 0, 0, 0);
        }
        __syncthreads();
    }
    // After the final barrier, no wave touches As/Bs again -> reusable.

    if (MODE == 0) {
        const int nw    = n0 + wn;
        const int which = nw >> 10;            // 0=Q 1=K 2=V
        const int hw    = (nw & 1023) >> 6;
        const int bbw   = (m0 + wm) >> 11;
        const int s0    = (m0 + wm) & 2047;

        // Wave-private 8KB LDS region carved from As/Bs (free after k-loop).
        char* W = (wave < 2) ? ((char*)As + wave * 8192)
                             : ((char*)Bs + (wave - 2) * 8192);

        if (which == 2) {
            // ---- V: LDS-transpose to [dh][s], then coalesced wide stores ----
#pragma unroll
            for (int ni = 0; ni < 4; ++ni) {
                const int dh = ni * 16 + col;
                const float bv = bias[nw + ni * 16 + col];
#pragma unroll
                for (int mi = 0; mi < 4; ++mi) {
                    unsigned short e0 = f2bf(acc[mi][ni][0] + bv);
                    unsigned short e1 = f2bf(acc[mi][ni][1] + bv);
                    unsigned short e2 = f2bf(acc[mi][ni][2] + bv);
                    unsigned short e3 = f2bf(acc[mi][ni][3] + bv);
                    uint2 pk;
                    pk.x = ((unsigned int)e1 << 16) | e0;
                    pk.y = ((unsigned int)e3 << 16) | e2;
                    int g = mi * 4 + quad;   // s_local granule (s=mi*16+quad*4+r)
                    *(uint2*)(W + dh * 128 + ((g ^ (dh & 7)) * 8)) = pk;
                }
            }
#pragma unroll
            for (int it = 0; it < 2; ++it) {
                const int dhr  = (lane >> 1) + it * 32;   // row 0..63
                const int half = lane & 1;                // 64B half of row
                uint2 gr[8];
#pragma unroll
                for (int j = 0; j < 8; ++j)
                    gr[j] = *(const uint2*)(W + dhr * 128 +
                              ((((half << 3) + j) ^ (dhr & 7)) * 8));
                unsigned short* dst = v + (((size_t)bbw * H_ + hw) * DH_ + dhr) * S_
                                        + s0 + half * 32;
                uint4 o0 = {gr[0].x, gr[0].y, gr[1].x, gr[1].y};
                uint4 o1 = {gr[2].x, gr[2].y, gr[3].x, gr[3].y};
                uint4 o2 = {gr[4].x, gr[4].y, gr[5].x, gr[5].y};
                uint4 o3 = {gr[6].x, gr[6].y, gr[7].x, gr[7].y};
                ((uint4*)dst)[0] = o0;
                ((uint4*)dst)[1] = o1;
                ((uint4*)dst)[2] = o2;
                ((uint4*)dst)[3] = o3;
            }
        } else {
            // ---- Q/K: reshape [s][dh] through LDS, contiguous 1KB stores ----
            unsigned short* dstb = (which == 0) ? q : k;
#pragma unroll
            for (int ni = 0; ni < 4; ++ni) {
                const float bv = bias[nw + ni * 16 + col];
#pragma unroll
                for (int mi = 0; mi < 4; ++mi) {
                    const int g = (2 * ni + (col >> 3)) ^ ((mi * 4 + quad) & 7);
#pragma unroll
                    for (int r = 0; r < 4; ++r) {
                        int row = mi * 16 + quad * 4 + r;
                        *(unsigned short*)(W + row * 128 + g * 16 + (col & 7) * 2)
                            = f2bf(acc[mi][ni][r] + bv);
                    }
                }
            }
            unsigned short* dst0 = dstb + (((size_t)bbw * H_ + hw) * S_ + s0) * DH_;
#pragma unroll
            for (int j = 0; j < 8; ++j) {
                int row = j * 8 + (lane >> 3);
                int g   = (lane & 7) ^ ((row >> 2) & 7);
                uint4 d = *(const uint4*)(W + row * 128 + g * 16);
                *(uint4*)(dst0 + row * DH_ + (lane & 7) * 8) = d;
            }
        }
    } else {
#pragma unroll
        for (int mi = 0; mi < 4; ++mi)
#pragma unroll
            for (int ni = 0; ni < 4; ++ni) {
                int n = n0 + wn + ni * 16 + col;
                float bv = bias[n];
#pragma unroll
                for (int r = 0; r < 4; ++r) {
                    int m = m0 + wm + mi * 16 + quad * 4 + r;
                    out[(size_t)m * N + n] = acc[mi][ni][r] + bv;
                }
            }
    }
}

// ---------------------------------------------------------------------------
// Flash-style MFMA attention, v12 = v5 + T14 async-STAGE split.
// v5's exposed stall: gll16 DMA issued ~100cy before the barrier that
// drains it (vmcnt(0) before s_barrier) -> full VMEM latency on critical
// path every tile. v12: K/V loaded into REGISTERS (4x dwordx4/lane, same
// addresses as the gll16 sources), issued right after bar1; ds_write'd to
// the SAME LDS layout at the top of the NEXT iteration. The vmcnt drain at
// bar2 lands a full compute phase after issue => covered. bar1 drains only
// fast ds_writes. Same 24KB LDS, same single buffer, same softmax path.
// Cost: 4 ds_write_b128/tile/lane, +16 VGPR (watch for occupancy cliff).
// Fragment layouts (validated): A[m][k]: m=lane&15,k=quad*8+j;
// B[k][n]: n=lane&15,k=quad*8+j; C/D: col(n)=lane&15, row(m)=quad*4+reg.
// ---------------------------------------------------------------------------
__global__ __launch_bounds__(256) void attn_mfma(
    const unsigned short* __restrict__ q, const unsigned short* __restrict__ k,
    const unsigned short* __restrict__ vT, const int* __restrict__ mask,
    unsigned short* __restrict__ ctx)
{
    __shared__ unsigned short Ks[64][64];      // [key][dh], swizzled granules
    __shared__ unsigned short Vt[64][64];      // [dh][key], swizzled granules
    __shared__ unsigned short Ps[4][16][64];   // per-wave P, swizzled granules

    const int tid  = threadIdx.x;
    const int wave = tid >> 6;
    const int lane = tid & 63;
    const int col  = lane & 15;
    const int quad = lane >> 4;

    const int h  = blockIdx.y;
    const int bb = blockIdx.z;
    const int q0 = blockIdx.x * 64 + wave * 16;
    const int kvbase = ((bb * H_ + h) * S_) * DH_;
    const int vtbase = ((bb * H_ + h) * DH_) * S_;

    // Q A-frags, pre-scaled by 1/sqrt(DH) * log2(e)
    const float SC = 0.18033688011112042f;
    const unsigned short* qrow = q + kvbase + (q0 + col) * DH_;
    ushort8 qr0 = *(const ushort8*)(qrow + quad * 8);
    ushort8 qr1 = *(const ushort8*)(qrow + 32 + quad * 8);
    short8 qa0, qa1;
#pragma unroll
    for (int j = 0; j < 8; ++j) {
        qa0[j] = (short)f2bf(bf2f(qr0[j]) * SC);
        qa1[j] = (short)f2bf(bf2f(qr1[j]) * SC);
    }
    const float MASKED = -1442.6951f;   // -1000*log2(e): exp2 -> exactly 0

    const int* mptr[4];
#pragma unroll
    for (int r = 0; r < 4; ++r)
        mptr[r] = mask + (bb * S_ + q0 + quad * 4 + r) * S_ + col;

    // staging geometry (byte-identical layout to the gll16 version):
    // wave<2 stage K rows [sw2*32,+32); wave>=2 stage V rows; granule scg.
    const int sw2   = wave & 1;
    const int srow0 = sw2 * 32 + (lane >> 3);
    const int scg   = (lane & 7) ^ (lane >> 3);
    const int sw0   = (quad ^ (col & 7)) * 8;        // swizzled frag offset, k<32
    const int sw1   = ((4 + quad) ^ (col & 7)) * 8;  // k>=32

    // per-lane global staging source / LDS dest
    const unsigned short* sbase = (wave < 2)
        ? (k  + kvbase + srow0 * DH_ + scg * 8)
        : (vT + vtbase + (size_t)srow0 * S_ + scg * 8);
    const int sstep  = (wave < 2) ? 8 * DH_ : 8 * S_;   // +8 rows per c
    const int ktstep = (wave < 2) ? 64 * DH_ : 64;      // per kv-tile advance
    char* sdst = ((wave < 2) ? (char*)Ks : (char*)Vt) + sw2 * 4096 + lane * 16;

    float4v oacc[4] = {};
    float rsum[4] = {0.f, 0.f, 0.f, 0.f};

    // prologue: issue loads for tile 0
    uint4 kreg[4];
#pragma unroll
    for (int c = 0; c < 4; ++c)
        kreg[c] = *(const uint4*)(sbase + c * sstep);

    for (int kt = 0; kt < S_ / 64; ++kt) {
        const int key0 = kt * 64;

        // ---- write staged regs -> LDS (vmcnt wait covered by prev compute) ----
#pragma unroll
        for (int c = 0; c < 4; ++c)
            *(uint4*)(sdst + c * 1024) = kreg[c];
        __syncthreads();   // bar1: lgkm drain only (ds_writes visible)

        // ---- issue next tile's staging loads (latency hides under compute) ----
        if (kt + 1 < S_ / 64) {
            const unsigned short* nb = sbase + (size_t)(kt + 1) * ktstep;
#pragma unroll
            for (int c = 0; c < 4; ++c)
                kreg[c] = *(const uint4*)(nb + c * sstep);
        }

        // ---- mask loads (latency covered by QK^T) ----
        int mk[4][4];
#pragma unroll
        for (int sub = 0; sub < 4; ++sub)
#pragma unroll
            for (int r = 0; r < 4; ++r)
                mk[sub][r] = mptr[r][key0 + sub * 16];

        // ---- QK^T (scores in exp2 domain) ----
        float4v sc[4];
#pragma unroll
        for (int sub = 0; sub < 4; ++sub) {
            short8 b0 = *(const short8*)&Ks[sub * 16 + col][sw0];
            short8 b1 = *(const short8*)&Ks[sub * 16 + col][sw1];
            float4v acs = {};
            acs = __builtin_amdgcn_mfma_f32_16x16x32_bf16(qa0, b0, acs, 0, 0, 0);
            acs = __builtin_amdgcn_mfma_f32_16x16x32_bf16(qa1, b1, acs, 0, 0, 0);
            sc[sub] = acs;
        }

        // ---- mask + exp2 + row-sum accumulate + pack P (swizzled) ----
#pragma unroll
        for (int sub = 0; sub < 4; ++sub)
#pragma unroll
        for (int r = 0; r < 4; ++r) {
            float s = (mk[sub][r] == 0) ? MASKED : sc[sub][r];
            float p = __builtin_amdgcn_exp2f(s);
            rsum[r] += p;
            int rowp = quad * 4 + r;
            int sg = (sub * 2 + (col >> 3)) ^ (rowp & 7);
            Ps[wave][rowp][sg * 8 + (col & 7)] = f2bf_hu(p);
        }
        // no barrier: Ps is wave-private (lgkmcnt ordering suffices)

        // ---- PV: O(16x64) += P(16x64) * V(64x64) ----
        short8 pa0 = *(const short8*)&Ps[wave][col][sw0];
        short8 pa1 = *(const short8*)&Ps[wave][col][sw1];
#pragma unroll
        for (int n = 0; n < 4; ++n) {
            short8 vb0 = *(const short8*)&Vt[n * 16 + col][sw0];
            short8 vb1 = *(const short8*)&Vt[n * 16 + col][sw1];
            oacc[n] = __builtin_amdgcn_mfma_f32_16x16x32_bf16(pa0, vb0, oacc[n], 0, 0, 0);
            oacc[n] = __builtin_amdgcn_mfma_f32_16x16x32_bf16(pa1, vb1, oacc[n], 0, 0, 0);
        }
        __syncthreads();   // bar2: Ks/Vt reads done; vmcnt drain covered by compute
    }

    // ---- final row-sum reduction + normalize + store ----
    float inv[4];
#pragma unroll
    for (int r = 0; r < 4; ++r) {
        float s = rsum[r];
#pragma unroll
        for (int msk = 1; msk < 16; msk <<= 1)
            s += __shfl_xor(s, msk);
        inv[r] = 1.0f / s;
    }
#pragma unroll
    for (int n = 0; n < 4; ++n)
#pragma unroll
    for (int r = 0; r < 4; ++r) {
        size_t off = ((size_t)bb * S_ + (q0 + quad * 4 + r)) * D_
                   + h * DH_ + n * 16 + col;
        ctx[off] = f2bf(oacc[n][r] * inv[r]);
    }
}

extern "C" void kernel_launch(void* const* d_in, const int* in_sizes, int n_in,
                              void* d_out, int out_size, void* d_ws, size_t ws_size,
                              hipStream_t stream)
{
    const float* x     = (const float*)d_in[0];
    const int*   mask  = (const int*)d_in[1];
    const float* w_qkv = (const float*)d_in[2];
    const float* b_qkv = (const float*)d_in[3];
    const float* w_out = (const float*)d_in[4];
    const float* b_out = (const float*)d_in[5];
    float* out = (float*)d_out;

    unsigned short* ws = (unsigned short*)d_ws;
    const size_t sz = (size_t)B_ * S_ * D_;   // 8,388,608 elements
    unsigned short* q     = ws;
    unsigned short* kk    = ws + sz;
    unsigned short* v     = ws + 2 * sz;      // vT layout [B][H][DH][S]
    unsigned short* ctx   = ws + 3 * sz;
    unsigned short* xbf   = ws + 4 * sz;
    unsigned short* wqkvT = ws + 5 * sz;                       // 3072*1024
    unsigned short* woutT = ws + 5 * sz + (size_t)N3_ * D_;    // 1024*1024

    convert_x<<<(int)(sz / (256 * 8)), 256, 0, stream>>>(x, xbf, (int)(sz / 8));
    convert_wT<<<dim3(N3_ / 32, D_ / 32), 256, 0, stream>>>(w_qkv, wqkvT, D_, N3_);
    convert_wT<<<dim3(D_ / 32, D_ / 32), 256, 0, stream>>>(w_out, woutT, D_, D_);

    gemm_bt<0><<<dim3(N3_ / 128, (B_ * S_) / 128), 256, 0, stream>>>(
        xbf, wqkvT, b_qkv, q, kk, v, nullptr, D_, N3_);

    attn_mfma<<<dim3(S_ / 64, H_, B_), 256, 0, stream>>>(q, kk, v, mask, ctx);

    gemm_bt<1><<<dim3(D_ / 128, (B_ * S_) / 128), 256, 0, stream>>>(
        ctx, woutT, b_out, nullptr, nullptr, nullptr, out, D_, D_);
}

// Round 9
// 366.600 us; speedup vs baseline: 1.7201x; 1.7201x over previous
//
#include <hip/hip_runtime.h>
#include <hip/hip_bf16.h>
#include <stdint.h>

// Problem constants
#define B_  4
#define S_  2048
#define D_  1024
#define H_  16
#define DH_ 64
#define N3_ 3072   // 3*D

typedef __attribute__((ext_vector_type(8))) short  short8;   // 8 bf16 (4 VGPRs)
typedef __attribute__((ext_vector_type(8))) unsigned short ushort8;
typedef __attribute__((ext_vector_type(4))) float  float4v;  // 4 fp32 acc

__device__ __forceinline__ float bf2f(unsigned short u) {
    union { unsigned int i; float f; } c; c.i = ((unsigned int)u) << 16; return c.f;
}
__device__ __forceinline__ unsigned short f2bf(float f) {
    union { float f; unsigned int i; } c; c.f = f;
    unsigned int x = c.i;
    return (unsigned short)((x + 0x7FFFu + ((x >> 16) & 1u)) >> 16);  // RNE
}
__device__ __forceinline__ unsigned short f2bf_hu(float f) {   // half-up (cheap)
    union { float f; unsigned int i; } c; c.f = f;
    return (unsigned short)((c.i + 0x8000u) >> 16);
}

// async global->LDS DMA, 16B per lane; LDS dest = wave-uniform base + lane*16
__device__ __forceinline__ void gll16(const void* g, void* l) {
    __builtin_amdgcn_global_load_lds(
        (const __attribute__((address_space(1))) unsigned int*)g,
        (__attribute__((address_space(3))) unsigned int*)l, 16, 0, 0);
}

// ---------------------------------------------------------------------------
// Fused preprocessing (R9): one launch replaces convert_x + 2x convert_wT.
// Flat grid, branch by block range (block-uniform divergence):
//   [0, 4096)            : x fp32 -> bf16, 8 elems/thread (exact cover)
//   [4096, 4096+3072)    : w_qkv [K=1024][N=3072] -> wqkvT [N][K], 32x32 tiles
//   [4096+3072, +1024)   : w_out [1024][1024] -> woutT, 32x32 tiles
// Saves 2 kernel launches + 2 graph dependency edges from the serial chain.
// ---------------------------------------------------------------------------
__global__ __launch_bounds__(256) void convert_all(
    const float* __restrict__ x, unsigned short* __restrict__ xbf,
    const float* __restrict__ w_qkv, unsigned short* __restrict__ wqkvT,
    const float* __restrict__ w_out, unsigned short* __restrict__ woutT)
{
    __shared__ float t[32][33];
    const int bid = blockIdx.x;

    if (bid < 4096) {
        int g = bid * 256 + threadIdx.x;     // 4096*256*8 = 8,388,608 exact
        const float4* p = (const float4*)(x + (size_t)g * 8);
        float4 a = p[0], b = p[1];
        ushort8 o;
        o[0] = f2bf(a.x); o[1] = f2bf(a.y); o[2] = f2bf(a.z); o[3] = f2bf(a.w);
        o[4] = f2bf(b.x); o[5] = f2bf(b.y); o[6] = f2bf(b.z); o[7] = f2bf(b.w);
        *(ushort8*)(xbf + (size_t)g * 8) = o;
        return;
    }

    const float* w; unsigned short* wt; int K, N, bx, by;
    if (bid < 4096 + 3072) {
        int b = bid - 4096;                  // w_qkv: 96 x 32 tile grid
        bx = b % 96; by = b / 96;
        w = w_qkv; wt = wqkvT; K = D_; N = N3_;
    } else {
        int b = bid - 4096 - 3072;           // w_out: 32 x 32 tile grid
        bx = b % 32; by = b / 32;
        w = w_out; wt = woutT; K = D_; N = D_;
    }
    const int row = threadIdx.x >> 5;   // 0..7
    const int col = threadIdx.x & 31;   // 0..31
    const int n0 = bx * 32;
    const int k0 = by * 32;
#pragma unroll
    for (int i = 0; i < 4; ++i)
        t[row + 8 * i][col] = w[(size_t)(k0 + row + 8 * i) * N + n0 + col];
    __syncthreads();
#pragma unroll
    for (int i = 0; i < 4; ++i)
        wt[(size_t)(n0 + row + 8 * i) * K + k0 + col] = f2bf(t[col][row + 8 * i]);
}

// ---------------------------------------------------------------------------
// bf16 MFMA GEMM: C[M,N] = A[M,K] @ Bt[N,K]^T + bias.
// 128x128 tile, BK=64, 4 waves, each wave 64x64 (4x4 MFMA tiles).
// Main loop: m97-structure, XOR-swizzled global_load_lds staging.
// MODE 0 epilogue: outputs routed through wave-private 8KB LDS region
//   (free after k-loop), stored with coalesced wide instructions:
//    - V  : transpose to [dh][s], 2x (4x dwordx4) per lane
//    - Q/K: reshape [s][dh], 8x 1KB dwordx4 stores
// MODE 1: fp32 out [M][N] (N=1024).
// ---------------------------------------------------------------------------
template <int MODE>
__global__ __launch_bounds__(256) void gemm_bt(
    const unsigned short* __restrict__ a, const unsigned short* __restrict__ bt,
    const float* __restrict__ bias,
    unsigned short* __restrict__ q, unsigned short* __restrict__ k,
    unsigned short* __restrict__ v, float* __restrict__ out,
    int K, int N)
{
    __shared__ unsigned short As[128][64];   // unpadded: 16 KB each
    __shared__ unsigned short Bs[128][64];

    const int tid  = threadIdx.x;
    const int wave = tid >> 6;
    const int lane = tid & 63;
    const int col  = lane & 15;
    const int quad = lane >> 4;
    const int wm   = (wave & 1) * 64;
    const int wn   = (wave >> 1) * 64;

    const int m0 = blockIdx.y * 128;
    const int n0 = blockIdx.x * 128;

    const int srow0 = wave * 32 + (lane >> 3);
    const int scg   = (lane & 7) ^ (lane >> 3);

    float4v acc[4][4] = {};

    for (int kt = 0; kt < K; kt += 64) {
#pragma unroll
        for (int c = 0; c < 4; ++c) {
            int row = srow0 + c * 8;
            gll16(a  + (size_t)(m0 + row) * K + kt + scg * 8,
                  (char*)As + wave * 4096 + c * 1024);
            gll16(bt + (size_t)(n0 + row) * K + kt + scg * 8,
                  (char*)Bs + wave * 4096 + c * 1024);
        }
        __syncthreads();   // drains vmcnt (incl. global_load_lds)

#pragma unroll
        for (int ks = 0; ks < 64; ks += 32) {
            const int sa = (((ks >> 3) + quad) ^ (col & 7)) * 8;  // swizzled offset
            short8 af[4], bf[4];
#pragma unroll
            for (int mi = 0; mi < 4; ++mi)
                af[mi] = *(const short8*)&As[wm + mi * 16 + col][sa];
#pragma unroll
            for (int ni = 0; ni < 4; ++ni)
                bf[ni] = *(const short8*)&Bs[wn + ni * 16 + col][sa];
#pragma unroll
            for (int mi = 0; mi < 4; ++mi)
#pragma unroll
                for (int ni = 0; ni < 4; ++ni)
                    acc[mi][ni] = __builtin_amdgcn_mfma_f32_16x16x32_bf16(
                        af[mi], bf[ni], acc[mi][ni], 0, 0, 0);
        }
        __syncthreads();
    }
    // After the final barrier, no wave touches As/Bs again -> reusable.

    if (MODE == 0) {
        const int nw    = n0 + wn;
        const int which = nw >> 10;            // 0=Q 1=K 2=V
        const int hw    = (nw & 1023) >> 6;
        const int bbw   = (m0 + wm) >> 11;
        const int s0    = (m0 + wm) & 2047;

        // Wave-private 8KB LDS region carved from As/Bs (free after k-loop).
        char* W = (wave < 2) ? ((char*)As + wave * 8192)
                             : ((char*)Bs + (wave - 2) * 8192);

        if (which == 2) {
            // ---- V: LDS-transpose to [dh][s], then coalesced wide stores ----
#pragma unroll
            for (int ni = 0; ni < 4; ++ni) {
                const int dh = ni * 16 + col;
                const float bv = bias[nw + ni * 16 + col];
#pragma unroll
                for (int mi = 0; mi < 4; ++mi) {
                    unsigned short e0 = f2bf(acc[mi][ni][0] + bv);
                    unsigned short e1 = f2bf(acc[mi][ni][1] + bv);
                    unsigned short e2 = f2bf(acc[mi][ni][2] + bv);
                    unsigned short e3 = f2bf(acc[mi][ni][3] + bv);
                    uint2 pk;
                    pk.x = ((unsigned int)e1 << 16) | e0;
                    pk.y = ((unsigned int)e3 << 16) | e2;
                    int g = mi * 4 + quad;   // s_local granule (s=mi*16+quad*4+r)
                    *(uint2*)(W + dh * 128 + ((g ^ (dh & 7)) * 8)) = pk;
                }
            }
#pragma unroll
            for (int it = 0; it < 2; ++it) {
                const int dhr  = (lane >> 1) + it * 32;   // row 0..63
                const int half = lane & 1;                // 64B half of row
                uint2 gr[8];
#pragma unroll
                for (int j = 0; j < 8; ++j)
                    gr[j] = *(const uint2*)(W + dhr * 128 +
                              ((((half << 3) + j) ^ (dhr & 7)) * 8));
                unsigned short* dst = v + (((size_t)bbw * H_ + hw) * DH_ + dhr) * S_
                                        + s0 + half * 32;
                uint4 o0 = {gr[0].x, gr[0].y, gr[1].x, gr[1].y};
                uint4 o1 = {gr[2].x, gr[2].y, gr[3].x, gr[3].y};
                uint4 o2 = {gr[4].x, gr[4].y, gr[5].x, gr[5].y};
                uint4 o3 = {gr[6].x, gr[6].y, gr[7].x, gr[7].y};
                ((uint4*)dst)[0] = o0;
                ((uint4*)dst)[1] = o1;
                ((uint4*)dst)[2] = o2;
                ((uint4*)dst)[3] = o3;
            }
        } else {
            // ---- Q/K: reshape [s][dh] through LDS, contiguous 1KB stores ----
            unsigned short* dstb = (which == 0) ? q : k;
#pragma unroll
            for (int ni = 0; ni < 4; ++ni) {
                const float bv = bias[nw + ni * 16 + col];
#pragma unroll
                for (int mi = 0; mi < 4; ++mi) {
                    const int g = (2 * ni + (col >> 3)) ^ ((mi * 4 + quad) & 7);
#pragma unroll
                    for (int r = 0; r < 4; ++r) {
                        int row = mi * 16 + quad * 4 + r;
                        *(unsigned short*)(W + row * 128 + g * 16 + (col & 7) * 2)
                            = f2bf(acc[mi][ni][r] + bv);
                    }
                }
            }
            unsigned short* dst0 = dstb + (((size_t)bbw * H_ + hw) * S_ + s0) * DH_;
#pragma unroll
            for (int j = 0; j < 8; ++j) {
                int row = j * 8 + (lane >> 3);
                int g   = (lane & 7) ^ ((row >> 2) & 7);
                uint4 d = *(const uint4*)(W + row * 128 + g * 16);
                *(uint4*)(dst0 + row * DH_ + (lane & 7) * 8) = d;
            }
        }
    } else {
#pragma unroll
        for (int mi = 0; mi < 4; ++mi)
#pragma unroll
            for (int ni = 0; ni < 4; ++ni) {
                int n = n0 + wn + ni * 16 + col;
                float bv = bias[n];
#pragma unroll
                for (int r = 0; r < 4; ++r) {
                    int m = m0 + wm + mi * 16 + quad * 4 + r;
                    out[(size_t)m * N + n] = acc[mi][ni][r] + bv;
                }
            }
    }
}

// ---------------------------------------------------------------------------
// Flash-style MFMA attention, v5 (EXACT — measured 164-165.5 us, 0 bank
// conflicts, 6 blocks/CU, MfmaUtil ~17.6, VALUBusy ~45, VGPR 64).
// CLOSED after 5 failed structural perturbations:
//   dbuf (R1: -2 blk/CU), swapped-QK^T P-path (R2: +2.1M conflicts),
//   2x q-rows (R3: spill 450MB; R4: -TLP), T14 reg-stage (R8: compiler
//   spilled the 16-reg staging array -> 355MB scratch writes, 2.6x slower).
// v5's 6-blocks/CU TLP covers staging latency better than anything
// expressible at HIP source level here.
// ---------------------------------------------------------------------------
__global__ __launch_bounds__(256) void attn_mfma(
    const unsigned short* __restrict__ q, const unsigned short* __restrict__ k,
    const unsigned short* __restrict__ vT, const int* __restrict__ mask,
    unsigned short* __restrict__ ctx)
{
    __shared__ unsigned short Ks[64][64];      // [key][dh], swizzled granules
    __shared__ unsigned short Vt[64][64];      // [dh][key], swizzled granules
    __shared__ unsigned short Ps[4][16][64];   // per-wave P, swizzled granules

    const int tid  = threadIdx.x;
    const int wave = tid >> 6;
    const int lane = tid & 63;
    const int col  = lane & 15;
    const int quad = lane >> 4;

    const int h  = blockIdx.y;
    const int bb = blockIdx.z;
    const int q0 = blockIdx.x * 64 + wave * 16;
    const int kvbase = ((bb * H_ + h) * S_) * DH_;
    const int vtbase = ((bb * H_ + h) * DH_) * S_;

    // Q A-frags, pre-scaled by 1/sqrt(DH) * log2(e)
    const float SC = 0.18033688011112042f;
    const unsigned short* qrow = q + kvbase + (q0 + col) * DH_;
    ushort8 qr0 = *(const ushort8*)(qrow + quad * 8);
    ushort8 qr1 = *(const ushort8*)(qrow + 32 + quad * 8);
    short8 qa0, qa1;
#pragma unroll
    for (int j = 0; j < 8; ++j) {
        qa0[j] = (short)f2bf(bf2f(qr0[j]) * SC);
        qa1[j] = (short)f2bf(bf2f(qr1[j]) * SC);
    }
    const float MASKED = -1442.6951f;   // -1000*log2(e): exp2 -> exactly 0

    const int* mptr[4];
#pragma unroll
    for (int r = 0; r < 4; ++r)
        mptr[r] = mask + (bb * S_ + q0 + quad * 4 + r) * S_ + col;

    // staging geometry (per half-wave-pair): rows [sw2*32, sw2*32+32)
    const int sw2   = wave & 1;
    const int srow0 = sw2 * 32 + (lane >> 3);
    const int scg   = (lane & 7) ^ (lane >> 3);
    const int sw0   = (quad ^ (col & 7)) * 8;        // swizzled frag offset, k<32
    const int sw1   = ((4 + quad) ^ (col & 7)) * 8;  // k>=32

    float4v oacc[4] = {};
    float rsum[4] = {0.f, 0.f, 0.f, 0.f};

    for (int kt = 0; kt < S_ / 64; ++kt) {
        const int key0 = kt * 64;

        // ---- hoist mask loads (latency hides behind staging + barrier) ----
        int mk[4][4];
#pragma unroll
        for (int sub = 0; sub < 4; ++sub)
#pragma unroll
            for (int r = 0; r < 4; ++r)
                mk[sub][r] = mptr[r][key0 + sub * 16];

        // ---- stage K and V^T via global_load_lds (waves 0,1=K; 2,3=V) ----
#pragma unroll
        for (int c = 0; c < 4; ++c) {
            int r = srow0 + c * 8;
            if (wave < 2)
                gll16(k + kvbase + (key0 + r) * DH_ + scg * 8,
                      (char*)Ks + sw2 * 4096 + c * 1024);
            else
                gll16(vT + vtbase + r * S_ + key0 + scg * 8,
                      (char*)Vt + sw2 * 4096 + c * 1024);
        }
        __syncthreads();

        // ---- QK^T (scores in exp2 domain) ----
        float4v sc[4];
#pragma unroll
        for (int sub = 0; sub < 4; ++sub) {
            short8 b0 = *(const short8*)&Ks[sub * 16 + col][sw0];
            short8 b1 = *(const short8*)&Ks[sub * 16 + col][sw1];
            float4v acs = {};
            acs = __builtin_amdgcn_mfma_f32_16x16x32_bf16(qa0, b0, acs, 0, 0, 0);
            acs = __builtin_amdgcn_mfma_f32_16x16x32_bf16(qa1, b1, acs, 0, 0, 0);
            sc[sub] = acs;
        }

        // ---- mask + exp2 + row-sum accumulate + pack P (swizzled) ----
#pragma unroll
        for (int sub = 0; sub < 4; ++sub)
#pragma unroll
        for (int r = 0; r < 4; ++r) {
            float s = (mk[sub][r] == 0) ? MASKED : sc[sub][r];
            float p = __builtin_amdgcn_exp2f(s);
            rsum[r] += p;
            int rowp = quad * 4 + r;
            int sg = (sub * 2 + (col >> 3)) ^ (rowp & 7);
            Ps[wave][rowp][sg * 8 + (col & 7)] = f2bf_hu(p);
        }
        // no barrier: Ps is wave-private (lgkmcnt ordering suffices)

        // ---- PV: O(16x64) += P(16x64) * V(64x64) ----
        short8 pa0 = *(const short8*)&Ps[wave][col][sw0];
        short8 pa1 = *(const short8*)&Ps[wave][col][sw1];
#pragma unroll
        for (int n = 0; n < 4; ++n) {
            short8 vb0 = *(const short8*)&Vt[n * 16 + col][sw0];
            short8 vb1 = *(const short8*)&Vt[n * 16 + col][sw1];
            oacc[n] = __builtin_amdgcn_mfma_f32_16x16x32_bf16(pa0, vb0, oacc[n], 0, 0, 0);
            oacc[n] = __builtin_amdgcn_mfma_f32_16x16x32_bf16(pa1, vb1, oacc[n], 0, 0, 0);
        }
        __syncthreads();   // Ks/Vt reads done before restage
    }

    // ---- final row-sum reduction + normalize + store ----
    float inv[4];
#pragma unroll
    for (int r = 0; r < 4; ++r) {
        float s = rsum[r];
#pragma unroll
        for (int msk = 1; msk < 16; msk <<= 1)
            s += __shfl_xor(s, msk);
        inv[r] = 1.0f / s;
    }
#pragma unroll
    for (int n = 0; n < 4; ++n)
#pragma unroll
    for (int r = 0; r < 4; ++r) {
        size_t off = ((size_t)bb * S_ + (q0 + quad * 4 + r)) * D_
                   + h * DH_ + n * 16 + col;
        ctx[off] = f2bf(oacc[n][r] * inv[r]);
    }
}

extern "C" void kernel_launch(void* const* d_in, const int* in_sizes, int n_in,
                              void* d_out, int out_size, void* d_ws, size_t ws_size,
                              hipStream_t stream)
{
    const float* x     = (const float*)d_in[0];
    const int*   mask  = (const int*)d_in[1];
    const float* w_qkv = (const float*)d_in[2];
    const float* b_qkv = (const float*)d_in[3];
    const float* w_out = (const float*)d_in[4];
    const float* b_out = (const float*)d_in[5];
    float* out = (float*)d_out;

    unsigned short* ws = (unsigned short*)d_ws;
    const size_t sz = (size_t)B_ * S_ * D_;   // 8,388,608 elements
    unsigned short* q     = ws;
    unsigned short* kk    = ws + sz;
    unsigned short* v     = ws + 2 * sz;      // vT layout [B][H][DH][S]
    unsigned short* ctx   = ws + 3 * sz;
    unsigned short* xbf   = ws + 4 * sz;
    unsigned short* wqkvT = ws + 5 * sz;                       // 3072*1024
    unsigned short* woutT = ws + 5 * sz + (size_t)N3_ * D_;    // 1024*1024

    // fused preprocessing: 4096 (x) + 3072 (w_qkv tiles) + 1024 (w_out tiles)
    convert_all<<<4096 + 3072 + 1024, 256, 0, stream>>>(
        x, xbf, w_qkv, wqkvT, w_out, woutT);

    gemm_bt<0><<<dim3(N3_ / 128, (B_ * S_) / 128), 256, 0, stream>>>(
        xbf, wqkvT, b_qkv, q, kk, v, nullptr, D_, N3_);

    attn_mfma<<<dim3(S_ / 64, H_, B_), 256, 0, stream>>>(q, kk, v, mask, ctx);

    gemm_bt<1><<<dim3(D_ / 128, (B_ * S_) / 128), 256, 0, stream>>>(
        ctx, woutT, b_out, nullptr, nullptr, nullptr, out, D_, D_);
}